// Round 1
// 89.821 us; speedup vs baseline: 1.1359x; 1.1359x over previous
//
#include <hip/hip_runtime.h>

// Signature_72327249265296: depth-4 path signature, path [64,512,10] fp32.
// out[b] = concat(A1[10], A2[100], A3[1000], A4[10000]).
//
// V2: segment-split for occupancy. The previous kernel had exactly 1024 waves
// (1 wave/SIMD, 9.5% occupancy) and was latency-bound (VALUBusy 33%).
// Signatures form a group under Chen's product, so:
//   kernel 1 (sig_partial): 4 segments x 128 steps per batch, each computes a
//     partial signature from zero state  -> 4096 waves = 16 waves/CU (50% occ).
//     Missing steps padded with dx=0 (exp(0) = identity, exact).
//   kernel 2 (sig_combine): folds the 4 partials per batch with Chen:
//     Z4[ijkl] = A4 + A3[ijk]B1[l] + A2[ij]B2[kl] + A1[i]B3[jkl] + B4[ijkl]
//     Z3[ijk]  = A3 + A2[ij]B1[k] + A1[i]B2[jk] + B3[ijk]
//     Z2[ij]   = A2 + A1 B1[j] + B2[ij]
//     Z1[i]    = A1 + B1[i]
// Per-increment Horner-collapsed step (unchanged from V1):
//   p1 = A1/6 + dx_i/24 ; q1 = A1/2 + dx_i/6 ; r1 = A1 + dx_i/2
//   p2 = A2/2 + p1*dx_j ; q2 = A2 + q1*dx_j  ; A2 += r1*dx_j
//   p3 = A3 + p2*dx_k   ;                      A3 += q2*dx_k
//   A1 += dx_i          ; A4[l] += p3*dx_l

#define CH      10
#define NSTEPS  511
#define ROW     12                 // padded dx row in floats (48 B, 16B-aligned)
#define SIGSZ   11110              // 10 + 100 + 1000 + 10000
#define NSEG    4
#define SEGLEN  128                // ceil(511/4); tail padded with zero rows
#define WSSEG   11112              // per-partial stride in floats (16B-aligned)

__global__ __launch_bounds__(256)
void sig_partial(const float* __restrict__ path, float* __restrict__ ws) {
    __shared__ __align__(16) float dxL[SEGLEN * ROW];

    const int tid  = threadIdx.x;
    const int b    = blockIdx.x >> 2;   // batch index 0..63
    const int part = blockIdx.x & 3;    // which 256-chain slice of the 1000
    const int seg  = blockIdx.y;        // segment 0..3
    const int s0   = seg * SEGLEN;

    // ---- stage this segment's increments into LDS (coalesced) ----
    const float* p = path + b * (512 * CH) + s0 * CH;
    for (int e = tid; e < SEGLEN * CH; e += 256) {
        int s = e / CH;
        int c = e - s * CH;
        dxL[s * ROW + c] = (s0 + s < NSTEPS) ? (p[e + CH] - p[e]) : 0.f;
    }
    __syncthreads();

    const int id = part * 256 + tid;    // chain id = i*100 + j*10 + k
    if (id < 1000) {
        const int ci = id / 100;
        const int cj = (id / 10) % 10;
        const int ck = id % 10;

        float a1 = 0.f, a2 = 0.f, a3 = 0.f;
        float a4[10];
        #pragma unroll
        for (int l = 0; l < 10; ++l) a4[l] = 0.f;

        #pragma unroll 4
        for (int s = 0; s < SEGLEN; ++s) {
            const float* row = dxL + s * ROW;
            // broadcast reads (all lanes same address -> conflict-free)
            const float4 d0 = *(const float4*)(row);
            const float4 d1 = *(const float4*)(row + 4);
            const float2 d2 = *(const float2*)(row + 8);
            // lane-indexed reads (<=10 distinct consecutive addrs -> distinct banks)
            const float dxi = row[ci];
            const float dxj = row[cj];
            const float dxk = row[ck];

            const float p1 = a1 * (1.f / 6.f)  + dxi * (1.f / 24.f);
            const float q1 = a1 * 0.5f         + dxi * (1.f / 6.f);
            const float r1 = a1                + dxi * 0.5f;
            const float p2 = a2 * 0.5f + p1 * dxj;
            const float q2 = a2        + q1 * dxj;
            a2 += r1 * dxj;
            const float p3 = a3 + p2 * dxk;
            a3 += q2 * dxk;
            a1 += dxi;

            a4[0] += p3 * d0.x; a4[1] += p3 * d0.y;
            a4[2] += p3 * d0.z; a4[3] += p3 * d0.w;
            a4[4] += p3 * d1.x; a4[5] += p3 * d1.y;
            a4[6] += p3 * d1.z; a4[7] += p3 * d1.w;
            a4[8] += p3 * d2.x; a4[9] += p3 * d2.y;
        }

        // ---- write this chain's share of the partial signature ----
        float* ob = ws + (b * NSEG + seg) * WSSEG;
        float* o4 = ob + 1110 + id * 10;
        #pragma unroll
        for (int l = 0; l < 10; ++l) o4[l] = a4[l];
        ob[110 + id] = a3;
        if (ck == 0)            ob[10 + ci * 10 + cj] = a2;
        if (ck == 0 && cj == 0) ob[ci] = a1;
    }
}

__global__ __launch_bounds__(256)
void sig_combine(const float* __restrict__ ws, float* __restrict__ out) {
    const int tid  = threadIdx.x;
    const int b    = blockIdx.x >> 2;
    const int part = blockIdx.x & 3;
    const int id   = part * 256 + tid;
    if (id >= 1000) return;

    const int ci = id / 100;
    const int cj = (id / 10) % 10;
    const int ck = id % 10;

    const float* w0 = ws + b * NSEG * WSSEG;

    // accumulator = segment-0 partial (every thread reads the level-1/2
    // values it needs; they were written once by the ck==0 / cj==ck==0 owners)
    float a1 = w0[ci];
    float a2 = w0[10 + ci * 10 + cj];
    float a3 = w0[110 + id];
    float a4[10];
    #pragma unroll
    for (int l = 0; l < 10; ++l) a4[l] = w0[1110 + id * 10 + l];

    #pragma unroll
    for (int s = 1; s < NSEG; ++s) {
        const float* wb = w0 + s * WSSEG;
        // scalar (runtime-indexed) loads kept as direct global loads, NOT a
        // local array index — avoids scratch (runtime-indexed reg arrays).
        const float b1i   = wb[ci];
        const float b1j   = wb[cj];
        const float b1k   = wb[ck];
        const float b2_ij = wb[10 + ci * 10 + cj];
        const float b2_jk = wb[10 + cj * 10 + ck];
        const float b3ijk = wb[110 + id];

        float b1v[10], b2k[10], b3jk[10], b4v[10];
        #pragma unroll
        for (int l = 0; l < 10; ++l) {
            b1v[l]  = wb[l];
            b2k[l]  = wb[10 + ck * 10 + l];
            b3jk[l] = wb[110 + (cj * 10 + ck) * 10 + l];
            b4v[l]  = wb[1110 + id * 10 + l];
        }

        // Z4 uses OLD a1,a2,a3 — computed before the lower levels update.
        #pragma unroll
        for (int l = 0; l < 10; ++l)
            a4[l] += a3 * b1v[l] + a2 * b2k[l] + a1 * b3jk[l] + b4v[l];
        a3 += a2 * b1k + a1 * b2_jk + b3ijk;
        a2 += a1 * b1j + b2_ij;
        a1 += b1i;
    }

    float* ob = out + b * SIGSZ;
    float* o4 = ob + 1110 + id * 10;
    #pragma unroll
    for (int l = 0; l < 10; ++l) o4[l] = a4[l];
    ob[110 + id] = a3;
    if (ck == 0)            ob[10 + ci * 10 + cj] = a2;
    if (ck == 0 && cj == 0) ob[ci] = a1;
}

extern "C" void kernel_launch(void* const* d_in, const int* in_sizes, int n_in,
                              void* d_out, int out_size, void* d_ws, size_t ws_size,
                              hipStream_t stream) {
    const float* path = (const float*)d_in[0];   // [64, 512, 10] fp32
    // d_in[1] = depth (=4), structure hard-coded above
    float* out = (float*)d_out;                  // [64, 11110] fp32
    float* ws  = (float*)d_ws;                   // 64*4*11112 floats = 11.4 MB

    sig_partial<<<dim3(256, NSEG), dim3(256), 0, stream>>>(path, ws);
    sig_combine<<<dim3(256), dim3(256), 0, stream>>>(ws, out);
}